// Round 7
// baseline (180.355 us; speedup 1.0000x reference)
//
#include <hip/hip_runtime.h>

// DeformUnfold R6: R5 pipeline + 4 blocks/CU occupancy (CPB 32->16, ROWS 23->15).
// Block = (batch, 4-row quad, 16-ch group), 512 threads, 1 sp each.
// Iter j: ds_write pair j+1 (regs loaded iter j-1), issue loads pair j+2,
// compute pair j, ONE barrier. Taps read as ds_read2_b32 pairs via x-remap.
// Rare out-of-window lanes (|offy|>~4, P~6e-5/tap) take exact global path.

constexpr int Bc = 8;
constexpr int Cc = 64;
constexpr int Hc = 128;
constexpr int Wc = 128;
constexpr int Kc = 9;
constexpr int HWc = 16384;
constexpr int ORc = 4;                // output rows per block
constexpr int ROWS = 15;              // staged window rows
constexpr int TILE = ROWS * Wc;       // 1920 floats (7.68 KB)
constexpr int TILE4 = TILE / 4;       // 480 float4
constexpr int CPB = 16;               // channels per block
constexpr int PAIRS = CPB / 2;        // 8 iterations
constexpr int MARG = 5;
constexpr int NT = 512;

__global__ __launch_bounds__(NT, 8) void deform_lds4(
    const float* __restrict__ x,
    const float* __restrict__ offset,
    float* __restrict__ out)
{
    __shared__ float buf[2][2][TILE];     // 30.7 KB -> 4 blocks/CU

    // XCD swizzle: batch b stays on XCD b (x per batch ~4.2MB ~ one L2)
    int wg = (int)((blockIdx.x & 7) * 128 + (blockIdx.x >> 3));
    int h  = wg & 3;                  // channel quarter
    int rq = (wg >> 2) & 31;          // row quad
    int b  = wg >> 7;

    int r0  = rq * ORc;
    int w0  = min(max(r0 - MARG, 0), Hc - ROWS);
    int tid = (int)threadIdx.x;
    int ho  = r0 + (tid >> 7);
    int wo  = tid & 127;
    int spg = r0 * Wc + tid;
    int ch0 = h * CPB;

    const float* offb = offset + (size_t)b * (2 * Kc) * HWc + spg;

    // ---- per-thread sampling meta (channel-independent) ----
    int   at[Kc], ab[Kc];
    float wA[Kc], wB[Kc], wyt[Kc], wyb[Kc];
    bool allok = true;
#pragma unroll
    for (int k = 0; k < Kc; ++k) {
        float offy = offb[(size_t)(2 * k) * HWc];
        float offx = offb[(size_t)(2 * k + 1) * HWc];
        float py = (float)(k / 3 + ho - 1) + offy;
        float px = (float)(k % 3 + wo - 1) + offx;
        float y0f = floorf(py), x0f = floorf(px);
        float ly = py - y0f, lx = px - x0f;
        float hy = 1.0f - ly, hx = 1.0f - lx;
        int y0 = (int)y0f, x0 = (int)x0f;
        int y1 = y0 + 1;

        bool vy0 = (unsigned)y0 < (unsigned)Hc;
        bool vy1 = (unsigned)y1 < (unsigned)Hc;
        wyt[k] = hy * (vy0 ? 1.0f : 0.0f);
        wyb[k] = ly * (vy1 ? 1.0f : 0.0f);

        int xb = min(max(x0, 0), Wc - 2);
        bool n  = (x0 == xb);
        bool lo = (x0 + 1 == xb);
        bool hi = (x0 == xb + 1);
        wA[k] = (n ? hx : 0.0f) + (lo ? lx : 0.0f);
        wB[k] = (n ? lx : 0.0f) + (hi ? hx : 0.0f);

        int y0c = min(max(y0, 0), Hc - 1);
        int y1c = min(max(y1, 0), Hc - 1);
        allok = allok & (y0c >= w0) & (y0c < w0 + ROWS)
                      & (y1c >= w0) & (y1c < w0 + ROWS);
        at[k] = (y0c - w0) * Wc + xb;
        ab[k] = (y1c - w0) * Wc + xb;
    }

    const float* xw = x + ((size_t)b * Cc + ch0) * HWc + (size_t)w0 * Wc;
    float* outb = out + (((size_t)b * Cc + ch0) * Kc) * (size_t)HWc + spg;

    // stage-pair helpers: pair p = channels (2p, 2p+1); 2 float4 per thread
    // (TILE4=480 < NT=512: second index tid+512 is always in plane 1)
    auto LOADP = [&](int p, float4& a0, float4& a1) {
        const float4* f0 = (const float4*)(xw + (size_t)(2 * p) * HWc);
        const float4* f1 = (const float4*)(xw + (size_t)(2 * p + 1) * HWc);
        a0 = (tid < TILE4) ? f0[tid] : f1[tid - TILE4];
        int i1 = tid + NT;
        if (i1 < 2 * TILE4) a1 = f1[i1 - TILE4];
    };
    auto WRITEP = [&](int pb, float4 a0, float4 a1) {
        float4* d0 = (float4*)buf[pb][0];
        float4* d1 = (float4*)buf[pb][1];
        if (tid < TILE4) d0[tid] = a0; else d1[tid - TILE4] = a0;
        int i1 = tid + NT;
        if (i1 < 2 * TILE4) d1[i1 - TILE4] = a1;
    };
    auto COMPUTE = [&](int pb, int p) {
        const float* B0 = buf[pb][0];
        const float* B1 = buf[pb][1];
        float* oc0 = outb + (size_t)(2 * p) * (Kc * HWc);
        float* oc1 = oc0 + (size_t)Kc * HWc;
        if (allok) {
#pragma unroll
            for (int k = 0; k < Kc; ++k) {
                float t00 = B0[at[k]], t01 = B0[at[k] + 1];   // ds_read2
                float u00 = B0[ab[k]], u01 = B0[ab[k] + 1];
                float t10 = B1[at[k]], t11 = B1[at[k] + 1];
                float u10 = B1[ab[k]], u11 = B1[ab[k] + 1];
                float v0 = wyt[k] * (wA[k] * t00 + wB[k] * t01)
                         + wyb[k] * (wA[k] * u00 + wB[k] * u01);
                float v1 = wyt[k] * (wA[k] * t10 + wB[k] * t11)
                         + wyb[k] * (wA[k] * u10 + wB[k] * u11);
                __builtin_nontemporal_store(v0, &oc0[(size_t)k * HWc]);
                __builtin_nontemporal_store(v1, &oc1[(size_t)k * HWc]);
            }
        } else {
            // rare: a clamped sample row fell outside the staged window
            const float* xc0 = x + ((size_t)b * Cc + ch0 + 2 * p) * HWc + w0 * Wc;
            const float* xc1 = xc0 + HWc;
#pragma unroll 1
            for (int k = 0; k < Kc; ++k) {
                float t00 = xc0[at[k]], t01 = xc0[at[k] + 1];
                float u00 = xc0[ab[k]], u01 = xc0[ab[k] + 1];
                float t10 = xc1[at[k]], t11 = xc1[at[k] + 1];
                float u10 = xc1[ab[k]], u11 = xc1[ab[k] + 1];
                float v0 = wyt[k] * (wA[k] * t00 + wB[k] * t01)
                         + wyb[k] * (wA[k] * u00 + wB[k] * u01);
                float v1 = wyt[k] * (wA[k] * t10 + wB[k] * t11)
                         + wyb[k] * (wA[k] * u10 + wB[k] * u11);
                oc0[(size_t)k * HWc] = v0;
                oc1[(size_t)k * HWc] = v1;
            }
        }
    };

    // ---- prologue ----
    float4 a0, a1, n0, n1;
    LOADP(0, a0, a1);
    WRITEP(0, a0, a1);
    LOADP(1, n0, n1);
    __syncthreads();

    // ---- main pipeline: ONE barrier per pair ----
    for (int j = 0; j < PAIRS; ++j) {
        int pb = j & 1;
        if (j + 1 < PAIRS) WRITEP(pb ^ 1, n0, n1);
        if (j + 2 < PAIRS) LOADP(j + 2, a0, a1);
        COMPUTE(pb, j);
        __syncthreads();
        n0 = a0; n1 = a1;
    }
}

extern "C" void kernel_launch(void* const* d_in, const int* in_sizes, int n_in,
                              void* d_out, int out_size, void* d_ws, size_t ws_size,
                              hipStream_t stream) {
    const float* x      = (const float*)d_in[0];
    const float* offset = (const float*)d_in[1];
    float* out          = (float*)d_out;

    int grid = Bc * (Hc / ORc) * (Cc / CPB);   // 8*32*4 = 1024 blocks
    deform_lds4<<<grid, NT, 0, stream>>>(x, offset, out);
}

// Round 8
// 71.201 us; speedup vs baseline: 2.5331x; 2.5331x over previous
//
#include <hip/hip_runtime.h>

// DeformUnfold R7: R5's proven 1-barrier pipeline (2 ch/iter, nt stores,
// launch_bounds(512,4) -> no spills) with the window shrunk 23->15 rows
// (MARG 5): x staging amplification 5.75x -> 3.75x, LDS 46 -> 30.7 KB.
// Block = (batch, 4-row quad, 32-ch half), 512 threads, 1 sp each.
// Rare lanes whose clamped sample rows miss the window (|offy|>~4,
// P ~ 6e-4 per thread) take an exact global slow path.

constexpr int Bc = 8;
constexpr int Cc = 64;
constexpr int Hc = 128;
constexpr int Wc = 128;
constexpr int Kc = 9;
constexpr int HWc = 16384;
constexpr int ORc = 4;                // output rows per block
constexpr int ROWS = 15;              // staged window rows
constexpr int TILE = ROWS * Wc;       // 1920 floats (7.68 KB)
constexpr int TILE4 = TILE / 4;       // 480 float4
constexpr int CPB = 32;               // channels per block
constexpr int PAIRS = CPB / 2;        // 16 iterations
constexpr int MARG = 5;
constexpr int NT = 512;

__global__ __launch_bounds__(NT, 4) void deform_lds5(
    const float* __restrict__ x,
    const float* __restrict__ offset,
    float* __restrict__ out)
{
    __shared__ float buf[2][2][TILE];     // 30.7 KB

    // XCD swizzle: batch b -> XCD b; consecutive wg on an XCD are the h=0/1
    // pair of the same row-quad (identical staging window -> L2 reuse).
    int wg = (int)((blockIdx.x & 7) * 64 + (blockIdx.x >> 3));
    int h  = wg & 1;
    int rq = (wg >> 1) & 31;
    int b  = wg >> 6;

    int r0  = rq * ORc;
    int w0  = min(max(r0 - MARG, 0), Hc - ROWS);
    int tid = (int)threadIdx.x;
    int ho  = r0 + (tid >> 7);
    int wo  = tid & 127;
    int spg = r0 * Wc + tid;
    int ch0 = h * CPB;

    const float* offb = offset + (size_t)b * (2 * Kc) * HWc + spg;

    // ---- per-thread sampling meta (channel-independent) ----
    int   at[Kc], ab[Kc];
    float wA[Kc], wB[Kc], wyt[Kc], wyb[Kc];
    bool allok = true;
#pragma unroll
    for (int k = 0; k < Kc; ++k) {
        float offy = offb[(size_t)(2 * k) * HWc];
        float offx = offb[(size_t)(2 * k + 1) * HWc];
        float py = (float)(k / 3 + ho - 1) + offy;
        float px = (float)(k % 3 + wo - 1) + offx;
        float y0f = floorf(py), x0f = floorf(px);
        float ly = py - y0f, lx = px - x0f;
        float hy = 1.0f - ly, hx = 1.0f - lx;
        int y0 = (int)y0f, x0 = (int)x0f;
        int y1 = y0 + 1;

        bool vy0 = (unsigned)y0 < (unsigned)Hc;
        bool vy1 = (unsigned)y1 < (unsigned)Hc;
        wyt[k] = hy * (vy0 ? 1.0f : 0.0f);
        wyb[k] = ly * (vy1 ? 1.0f : 0.0f);

        int xb = min(max(x0, 0), Wc - 2);
        bool n  = (x0 == xb);
        bool lo = (x0 + 1 == xb);
        bool hi = (x0 == xb + 1);
        wA[k] = (n ? hx : 0.0f) + (lo ? lx : 0.0f);
        wB[k] = (n ? lx : 0.0f) + (hi ? hx : 0.0f);

        int y0c = min(max(y0, 0), Hc - 1);
        int y1c = min(max(y1, 0), Hc - 1);
        allok = allok & (y0c >= w0) & (y0c < w0 + ROWS)
                      & (y1c >= w0) & (y1c < w0 + ROWS);
        at[k] = (y0c - w0) * Wc + xb;
        ab[k] = (y1c - w0) * Wc + xb;
    }

    const float* xw = x + ((size_t)b * Cc + ch0) * HWc + (size_t)w0 * Wc;
    float* outb = out + (((size_t)b * Cc + ch0) * Kc) * (size_t)HWc + spg;

    // stage-pair helpers: pair p = channels (2p, 2p+1); 2 float4 per thread
    // (TILE4=480 < NT=512: index tid+512 is always in plane 1)
    auto LOADP = [&](int p, float4& a0, float4& a1) {
        const float4* f0 = (const float4*)(xw + (size_t)(2 * p) * HWc);
        const float4* f1 = (const float4*)(xw + (size_t)(2 * p + 1) * HWc);
        a0 = (tid < TILE4) ? f0[tid] : f1[tid - TILE4];
        int i1 = tid + NT;
        if (i1 < 2 * TILE4) a1 = f1[i1 - TILE4];
    };
    auto WRITEP = [&](int pb, float4 a0, float4 a1) {
        float4* d0 = (float4*)buf[pb][0];
        float4* d1 = (float4*)buf[pb][1];
        if (tid < TILE4) d0[tid] = a0; else d1[tid - TILE4] = a0;
        int i1 = tid + NT;
        if (i1 < 2 * TILE4) d1[i1 - TILE4] = a1;
    };
    auto COMPUTE = [&](int pb, int p) {
        const float* B0 = buf[pb][0];
        const float* B1 = buf[pb][1];
        float* oc0 = outb + (size_t)(2 * p) * (Kc * HWc);
        float* oc1 = oc0 + (size_t)Kc * HWc;
        if (allok) {
#pragma unroll
            for (int k = 0; k < Kc; ++k) {
                float t00 = B0[at[k]], t01 = B0[at[k] + 1];   // ds_read2
                float u00 = B0[ab[k]], u01 = B0[ab[k] + 1];
                float t10 = B1[at[k]], t11 = B1[at[k] + 1];
                float u10 = B1[ab[k]], u11 = B1[ab[k] + 1];
                float v0 = wyt[k] * (wA[k] * t00 + wB[k] * t01)
                         + wyb[k] * (wA[k] * u00 + wB[k] * u01);
                float v1 = wyt[k] * (wA[k] * t10 + wB[k] * t11)
                         + wyb[k] * (wA[k] * u10 + wB[k] * u11);
                __builtin_nontemporal_store(v0, &oc0[(size_t)k * HWc]);
                __builtin_nontemporal_store(v1, &oc1[(size_t)k * HWc]);
            }
        } else {
            // rare: a clamped sample row fell outside the staged window
            const float* xc0 = x + ((size_t)b * Cc + ch0 + 2 * p) * HWc + w0 * Wc;
            const float* xc1 = xc0 + HWc;
#pragma unroll 1
            for (int k = 0; k < Kc; ++k) {
                float t00 = xc0[at[k]], t01 = xc0[at[k] + 1];
                float u00 = xc0[ab[k]], u01 = xc0[ab[k] + 1];
                float t10 = xc1[at[k]], t11 = xc1[at[k] + 1];
                float u10 = xc1[ab[k]], u11 = xc1[ab[k] + 1];
                float v0 = wyt[k] * (wA[k] * t00 + wB[k] * t01)
                         + wyb[k] * (wA[k] * u00 + wB[k] * u01);
                float v1 = wyt[k] * (wA[k] * t10 + wB[k] * t11)
                         + wyb[k] * (wA[k] * u10 + wB[k] * u11);
                oc0[(size_t)k * HWc] = v0;
                oc1[(size_t)k * HWc] = v1;
            }
        }
    };

    // ---- prologue: stage pair 0, preload pair 1 ----
    float4 a0, a1, n0, n1;
    LOADP(0, a0, a1);
    WRITEP(0, a0, a1);
    LOADP(1, n0, n1);
    __syncthreads();

    // ---- main pipeline: ONE barrier per pair ----
    for (int j = 0; j < PAIRS; ++j) {
        int pb = j & 1;
        if (j + 1 < PAIRS) WRITEP(pb ^ 1, n0, n1);   // pair j+1 -> other buf
        if (j + 2 < PAIRS) LOADP(j + 2, a0, a1);     // issue pair j+2
        COMPUTE(pb, j);
        __syncthreads();
        n0 = a0; n1 = a1;
    }
}

extern "C" void kernel_launch(void* const* d_in, const int* in_sizes, int n_in,
                              void* d_out, int out_size, void* d_ws, size_t ws_size,
                              hipStream_t stream) {
    const float* x      = (const float*)d_in[0];
    const float* offset = (const float*)d_in[1];
    float* out          = (float*)d_out;

    int grid = Bc * (Hc / ORc) * (Cc / CPB);   // 8*32*2 = 512 blocks
    deform_lds5<<<grid, NT, 0, stream>>>(x, offset, out);
}